// Round 6
// baseline (252.424 us; speedup 1.0000x reference)
//
#include <hip/hip_runtime.h>
#include <hip/hip_bf16.h>
#include <math.h>

// STGCN fused, MFMA version, round 6.
// Round 5 post-mortem: dur flat at 145us while VALUBusy fell 66->49% => the
// kernel is LATENCY-bound (9 serialized weight-load->MFMA->barrier stages,
// only 2 blocks/CU to overlap them). Fix: NP 32->16 halves LDS (53.7->26.9KB)
// -> 4 blocks/CU (32 waves, 100% occupancy cap), launch_bounds(512,8) keeps
// VGPR<=64 so the wave cap is reachable. Per-pair layouts unchanged; only
// wave->tile mappings and grid change.

namespace {

constexpr int NT = 512;               // 8 waves
constexpr int NP = 16;                // (b,n) pairs per block (same n)
constexpr float INV_STD = 0.9999950000374997f; // 1/sqrt(1+1e-5)

typedef __attribute__((ext_vector_type(8))) short bf16x8;
typedef __attribute__((ext_vector_type(4))) float f32x4;

// d_ws layout (bf16 element offsets). All sections 16B-aligned (off%8==0).
constexpr int OFF_CHEB_A = 0;         // [32co][32k]
constexpr int OFF_CHEB_B = 1024;      // [32co][32k]
constexpr int OFF_A2     = 2048;      // P,Q,R x [64co][96k]
constexpr int OFF_B1     = 20480;     // P,Q,R x [32co][192k]
constexpr int OFF_B2     = 38912;     // P,Q,R x [16co][96k]
constexpr int OFF_S1B    = 43520;     // P,Q,R x [32co][32k] (zero-padded K)
constexpr int OFF_W1     = 46592;     // 113 x [64h][32k]
constexpr int OFF_W2     = 278016;    // 113 x [3o][64k]
// total ws bytes needed: (278016 + 21696) * 2 = 599,424

__device__ __forceinline__ unsigned short f2bf(float f){   // RNE f32->bf16 (prep)
  unsigned int u = __float_as_uint(f);
  u += 0x7fffu + ((u >> 16) & 1u);
  return (unsigned short)(u >> 16);
}
__device__ __forceinline__ unsigned short f2bf_fast(float f){  // native RNE
  return __bfloat16_as_ushort(__float2bfloat16(f));
}
__device__ __forceinline__ f32x4 bcast(float v){ f32x4 r; r[0]=v; r[1]=v; r[2]=v; r[3]=v; return r; }

struct Params {
  const float *x;
  const float *awp,*abp,*awq,*abq,*awr,*abr,*acw,*acb;
  const float *awp2,*abp2,*awq2,*abq2,*awr2,*abr2,*ag,*abeta;
  const float *bwp,*bbp,*bwq,*bbq,*bwr,*bbr,*bcw,*bcb;
  const float *bwp2,*bbp2,*bwq2,*bbq2,*bwr2,*bbr2,*bg,*bbeta;
  const float *w1,*b1,*w2,*b2;
  float *out;
};

// ---------------- prep: one-time weight transpose/convert into ws ----------------
__global__ void stgcn_prep(const Params p, unsigned short* __restrict__ W)
{
  int e = blockIdx.x*256 + threadIdx.x;
  if (e < 2048){                                    // cheb a/b [ci][co] -> [co][ci]
    const float* src = (e < 1024) ? p.acw : p.bcw;
    const int j = e & 1023, co = j >> 5, k = j & 31;
    W[e] = f2bf(src[k*32 + co]);
    return;
  }
  e -= 2048;
  if (e < 18432){                                   // a2: 3 x [64co][96k]
    const int mat = e / 6144, j = e % 6144, co = j / 96, k = j % 96;
    const float* src = mat==0 ? p.awp2 : (mat==1 ? p.awq2 : p.awr2);
    W[OFF_A2 + e] = f2bf(src[k*64 + co]);
    return;
  }
  e -= 18432;
  if (e < 18432){                                   // b1: 3 x [32co][192k]
    const int mat = e / 6144, j = e % 6144, co = j / 192, k = j % 192;
    const float* src = mat==0 ? p.bwp : (mat==1 ? p.bwq : p.bwr);
    W[OFF_B1 + e] = f2bf(src[k*32 + co]);
    return;
  }
  e -= 18432;
  if (e < 4608){                                    // b2: 3 x [16co][96k]
    const int mat = e / 1536, j = e % 1536, co = j / 96, k = j % 96;
    const float* src = mat==0 ? p.bwp2 : (mat==1 ? p.bwq2 : p.bwr2);
    W[OFF_B2 + e] = f2bf(src[k*16 + co]);
    return;
  }
  e -= 4608;
  if (e < 3072){                                    // s1: 3 x [32co][32k], k=tt*8+ci
    const int mat = e / 1024, j = e % 1024, co = j >> 5, k = j & 31;
    const int tt = k >> 3, ci = k & 7;
    const float* src = mat==0 ? p.awp : (mat==1 ? p.awq : p.awr);
    W[OFF_S1B + e] = (ci < 4 && tt < 3) ? f2bf(src[(tt*4+ci)*32 + co])
                                        : (unsigned short)0;
    return;
  }
  e -= 3072;
  if (e < 231424){ W[OFF_W1 + e] = f2bf(p.w1[e]); return; }  // [n][h][f] already B^T
  e -= 231424;
  if (e < 21696){ W[OFF_W2 + e] = f2bf(p.w2[e]); }           // [n][o][k] already B^T
}

// ---------------- generic MFMA stage (j-outer, B preloaded) ----------------
// A row m=(pr,t) in LDS; k-step ks reads 32 contiguous bf16.
// EPI: 0 = relu(acc+bias); 1 = relu(P*sig(Q)+R); 2 = EPI1 then relu(v*bnsc+bnbt).
template<int TOUT, int CIN, int COUT, int NK, int RSTI, int PSTI, int RSTO, int PSTO,
         int KP, int EPI, int MJOBS, int MSTEP>
__device__ __forceinline__ void mfma_stage(const unsigned short* __restrict__ aB,
    const unsigned short* __restrict__ gW, unsigned short* __restrict__ oB,
    const float* __restrict__ gb0, const float* __restrict__ gb1,
    const float* __restrict__ gb2,
    const int Mtile0, const int Ntile, const int lm, const int lk,
    const float bnsc, const float bnbt)
{
  const int col = Ntile*16 + lm;
  bf16x8 wp[NK], wq[NK], wr[NK];
  const unsigned short* wbase = gW + col*KP + lk*8;
  #pragma unroll
  for (int ks = 0; ks < NK; ++ks){
    wp[ks] = *reinterpret_cast<const bf16x8*>(wbase + ks*32);
    if constexpr (EPI >= 1){
      wq[ks] = *reinterpret_cast<const bf16x8*>(wbase +   COUT*KP + ks*32);
      wr[ks] = *reinterpret_cast<const bf16x8*>(wbase + 2*COUT*KP + ks*32);
    }
  }
  const float b0 = gb0[col];
  float b1v = 0.f, b2v = 0.f;
  if constexpr (EPI >= 1){ b1v = gb1[col]; b2v = gb2[col]; }

  #pragma unroll
  for (int j = 0; j < MJOBS; ++j){
    const int Mtile = Mtile0 + j*MSTEP;
    const int m  = Mtile*16 + lm;
    const int pr = m / TOUT;
    const int t  = m - pr*TOUT;
    f32x4 aP = bcast(b0), aQ, aR;
    if constexpr (EPI >= 1){ aQ = bcast(b1v); aR = bcast(b2v); }
    #pragma unroll
    for (int ks = 0; ks < NK; ++ks){
      int elem;
      if constexpr (CIN == 32) elem = pr*PSTI + (t + ks)*RSTI + lk*8;
      else                     elem = pr*PSTI + (t + (ks>>1))*RSTI + (ks&1)*32 + lk*8;
      const bf16x8 a = *reinterpret_cast<const bf16x8*>(aB + elem);
      aP = __builtin_amdgcn_mfma_f32_16x16x32_bf16(a, wp[ks], aP, 0, 0, 0);
      if constexpr (EPI >= 1){
        aQ = __builtin_amdgcn_mfma_f32_16x16x32_bf16(a, wq[ks], aQ, 0, 0, 0);
        aR = __builtin_amdgcn_mfma_f32_16x16x32_bf16(a, wr[ks], aR, 0, 0, 0);
      }
    }
    #pragma unroll
    for (int r = 0; r < 4; ++r){
      const int mo = Mtile*16 + lk*4 + r;
      const int po = mo / TOUT;
      const int to = mo - po*TOUT;
      float v;
      if constexpr (EPI == 0) v = fmaxf(aP[r], 0.f);
      else {
        const float sig = 1.f/(1.f + __expf(-aQ[r]));
        v = fmaxf(fmaf(aP[r], sig, aR[r]), 0.f);
        if constexpr (EPI == 2) v = fmaxf(fmaf(v, bnsc, bnbt), 0.f);
      }
      oB[po*PSTO + to*RSTO + col] = f2bf_fast(v);
    }
  }
}

// ---------------- stage4 (K=192): k-outer, single job/wave, 9 B-frags live ----------------
__device__ __forceinline__ void mfma_stage4(const unsigned short* __restrict__ aB,
    const unsigned short* __restrict__ gW, unsigned short* __restrict__ oB,
    const float* __restrict__ gb0, const float* __restrict__ gb1,
    const float* __restrict__ gb2,
    const int Mtile, const int Ntile, const int lm, const int lk)
{
  const int col = Ntile*16 + lm;
  const unsigned short* wbase = gW + col*192 + lk*8;
  f32x4 aP = bcast(gb0[col]), aQ = bcast(gb1[col]), aR = bcast(gb2[col]);
  const int m  = Mtile*16 + lm;
  const int pr = m >> 2, t = m & 3;
  #pragma unroll
  for (int kb = 0; kb < 2; ++kb){
    bf16x8 wp[3], wq[3], wr[3];
    #pragma unroll
    for (int s = 0; s < 3; ++s){
      const int ks = kb*3 + s;
      wp[s] = *reinterpret_cast<const bf16x8*>(wbase +         ks*32);
      wq[s] = *reinterpret_cast<const bf16x8*>(wbase +  6144 + ks*32); // 32*192
      wr[s] = *reinterpret_cast<const bf16x8*>(wbase + 12288 + ks*32);
    }
    #pragma unroll
    for (int s = 0; s < 3; ++s){
      const int ks = kb*3 + s;
      const int elem = pr*432 + (t + (ks>>1))*72 + (ks&1)*32 + lk*8;
      const bf16x8 a = *reinterpret_cast<const bf16x8*>(aB + elem);
      aP = __builtin_amdgcn_mfma_f32_16x16x32_bf16(a, wp[s], aP, 0,0,0);
      aQ = __builtin_amdgcn_mfma_f32_16x16x32_bf16(a, wq[s], aQ, 0,0,0);
      aR = __builtin_amdgcn_mfma_f32_16x16x32_bf16(a, wr[s], aR, 0,0,0);
    }
  }
  #pragma unroll
  for (int r = 0; r < 4; ++r){
    const int mo = Mtile*16 + lk*4 + r;
    const int po = mo >> 2, to = mo & 3;
    const float sig = 1.f/(1.f + __expf(-aQ[r]));
    const float v = fmaxf(fmaf(aP[r], sig, aR[r]), 0.f);
    oB[po*160 + to*40 + col] = f2bf_fast(v);
  }
}

// ---------------- main fused kernel ----------------
// LDS: sxb 2816B + bufA 13824B + bufB 10240B = 26880B -> 4 blocks/CU (wave cap).
// launch_bounds(512,8): VGPR cap 64 so 32 waves/CU schedulable.
// Layouts (bf16 elems): sxb [pr*88 + t*8 + ci] (ci<4 real, rest 0, t=10 zero);
// h1/h1c [pr*320 + t*40 + c] (8t,32c); h2 [pr*432 + t*72 + c] (6t,64c);
// h3/h3c [pr*160 + t*40 + c] (4t,32c); h4 [pr*40 + t*16 + c] (flatten order);
// hid [pr*72 + h].
__global__ __launch_bounds__(NT, 8) void stgcn_main(const Params p,
    const unsigned short* __restrict__ W)
{
  __shared__ unsigned short sxb[NP*88];    // 2816 B
  __shared__ unsigned short bufA[6912];    // 13824 B (max: h2 16x432)
  __shared__ unsigned short bufB[5120];    // 10240 B (max: h1c 16x320)

  const int tid = threadIdx.x;
  const int l   = tid & 63;
  const int wid = tid >> 6;     // 0..7
  const int lm  = l & 15;
  const int lk  = l >> 4;
  const int n   = blockIdx.x >> 6;          // b-fastest: 64 consecutive blocks
  const int b0  = (blockIdx.x & 63) * NP;   // share one n (weights L2-hot)

  // x tile: one 8B chunk per (pr, half-slot); even chunks get bf16(x), odd zeros
  for (int i = tid; i < NP*22; i += NT){
    const int pr = i / 22, c = i - pr*22;
    const int t  = c >> 1;
    unsigned short v0=0,v1=0,v2=0,v3=0;
    if (!(c & 1) && t < 10){
      const float4 xf = *reinterpret_cast<const float4*>(
          &p.x[(size_t)(((b0+pr)*10 + t)*113 + n)*4]);
      v0 = f2bf(xf.x); v1 = f2bf(xf.y); v2 = f2bf(xf.z); v3 = f2bf(xf.w);
    }
    ushort4 pk; pk.x=v0; pk.y=v1; pk.z=v2; pk.w=v3;
    *reinterpret_cast<ushort4*>(&sxb[i*4]) = pk;
  }
  __syncthreads();

  // stage1: (10,4)->(8,32) gated conv, K padded 12->32. M=128(8) N=32(2) -> bufA
  mfma_stage<8,32,32,1, 8,88, 40,320, 32, 1, 2,4>(
      sxb, W+OFF_S1B, bufA, p.abp, p.abq, p.abr, wid>>1, wid&1, lm, lk, 0.f, 0.f);
  __syncthreads();

  // cheb1: M=128(8) N=32(2) K=32 -> bufB
  mfma_stage<8,32,32,1, 40,320, 40,320, 32, 0, 2,4>(
      bufA, W+OFF_CHEB_A, bufB, p.acb, p.acb, p.acb, wid>>1, wid&1, lm, lk, 0.f, 0.f);
  __syncthreads();

  // stage3: (8,32)->(6,64) gated + BN(a). M=96(6) N=64(4) K=96 -> bufA
  {
    const float bnsc = INV_STD * p.ag[n], bnbt = p.abeta[n];
    mfma_stage<6,32,64,3, 40,320, 72,432, 96, 2, 3,2>(
        bufB, W+OFF_A2, bufA, p.abp2, p.abq2, p.abr2, wid>>2, wid&3, lm, lk, bnsc, bnbt);
  }
  __syncthreads();

  // stage4: (6,64)->(4,32) gated. M=64(4) N=32(2) K=192 -> bufB
  mfma_stage4(bufA, W+OFF_B1, bufB, p.bbp, p.bbq, p.bbr, wid>>1, wid&1, lm, lk);
  __syncthreads();

  // cheb2: M=64(4) N=32(2) K=32 -> bufA
  mfma_stage<4,32,32,1, 40,160, 40,160, 32, 0, 1,1>(
      bufB, W+OFF_CHEB_B, bufA, p.bcb, p.bcb, p.bcb, wid>>1, wid&1, lm, lk, 0.f, 0.f);
  __syncthreads();

  // stage6: (4,32)->(2,16) gated + BN(b). M=32(2) N=16(1) K=96 -> bufB (h4)
  if (wid < 2){
    const float bnsc = INV_STD * p.bg[n], bnbt = p.bbeta[n];
    mfma_stage<2,32,16,3, 40,160, 16,40, 96, 2, 1,1>(
        bufA, W+OFF_B2, bufB, p.bbp2, p.bbq2, p.bbr2, wid, 0, lm, lk, bnsc, bnbt);
  }
  __syncthreads();

  // mlp1: feat(32) -> hid(64). M=16(1) N=64(4) K=32 -> bufA
  if (wid < 4){
    mfma_stage<1,32,64,1, 16,40, 16,72, 32, 0, 1,1>(
        bufB, W+OFF_W1 + n*2048, bufA, p.b1 + n*64, p.b1, p.b1, 0, wid, lm, lk, 0.f, 0.f);
  }
  __syncthreads();

  // mlp2: hid(64) -> 3. M=16(1), cols 0..2 valid. Store f32 to global.
  if (wid == 0){
    const unsigned short* WM2 = W + OFF_W2 + n*192;
    const float bias = (lm < 3) ? p.b2[n*3 + lm] : 0.f;
    f32x4 acc = bcast(bias);
    #pragma unroll
    for (int ks = 0; ks < 2; ++ks){
      const bf16x8 a = *reinterpret_cast<const bf16x8*>(bufA + lm*72 + ks*32 + lk*8);
      const bf16x8 b = *reinterpret_cast<const bf16x8*>(WM2 + lm*64 + ks*32 + lk*8);
      acc = __builtin_amdgcn_mfma_f32_16x16x32_bf16(a, b, acc, 0, 0, 0);
    }
    if (lm < 3){
      #pragma unroll
      for (int r = 0; r < 4; ++r){
        const int pr = lk*4 + r;
        p.out[(size_t)((b0+pr)*113 + n)*3 + lm] = acc[r];
      }
    }
  }
}

} // namespace

extern "C" void kernel_launch(void* const* d_in, const int* in_sizes, int n_in,
                              void* d_out, int out_size, void* d_ws, size_t ws_size,
                              hipStream_t stream) {
  (void)in_sizes; (void)n_in; (void)ws_size; (void)out_size;
  Params p;
  p.x     = (const float*)d_in[0];
  // d_in[1] = edge_index (unused: ChebConv K=1 keeps only the identity term)
  p.awp   = (const float*)d_in[2];  p.abp   = (const float*)d_in[3];
  p.awq   = (const float*)d_in[4];  p.abq   = (const float*)d_in[5];
  p.awr   = (const float*)d_in[6];  p.abr   = (const float*)d_in[7];
  p.acw   = (const float*)d_in[8];  p.acb   = (const float*)d_in[9];
  p.awp2  = (const float*)d_in[10]; p.abp2  = (const float*)d_in[11];
  p.awq2  = (const float*)d_in[12]; p.abq2  = (const float*)d_in[13];
  p.awr2  = (const float*)d_in[14]; p.abr2  = (const float*)d_in[15];
  p.ag    = (const float*)d_in[16]; p.abeta = (const float*)d_in[17];
  p.bwp   = (const float*)d_in[18]; p.bbp   = (const float*)d_in[19];
  p.bwq   = (const float*)d_in[20]; p.bbq   = (const float*)d_in[21];
  p.bwr   = (const float*)d_in[22]; p.bbr   = (const float*)d_in[23];
  p.bcw   = (const float*)d_in[24]; p.bcb   = (const float*)d_in[25];
  p.bwp2  = (const float*)d_in[26]; p.bbp2  = (const float*)d_in[27];
  p.bwq2  = (const float*)d_in[28]; p.bbq2  = (const float*)d_in[29];
  p.bwr2  = (const float*)d_in[30]; p.bbr2  = (const float*)d_in[31];
  p.bg    = (const float*)d_in[32]; p.bbeta = (const float*)d_in[33];
  p.w1    = (const float*)d_in[34]; p.b1    = (const float*)d_in[35];
  p.w2    = (const float*)d_in[36]; p.b2    = (const float*)d_in[37];
  p.out   = (float*)d_out;

  unsigned short* W = (unsigned short*)d_ws;   // needs 599,424 bytes

  // prep: 299,712 work items
  stgcn_prep<<<1171, 256, 0, stream>>>(p, W);

  const int tiles = 113 * 64;  // 7232 blocks, b fastest within each n
  stgcn_main<<<tiles, NT, 0, stream>>>(p, W);
}

// Round 7
// 221.213 us; speedup vs baseline: 1.1411x; 1.1411x over previous
//
#include <hip/hip_runtime.h>
#include <hip/hip_bf16.h>
#include <math.h>

// STGCN fused, MFMA version, round 7.
// Round 6 post-mortem: launch_bounds(512,8) made the compiler allocate only
// 32 arch-VGPRs (unified VGPR/AGPR split) -> 397MB scratch spill, 252us.
// Round 7 = round 6 structure (NP=16, LDS 26.9KB) with round 5's proven
// launch_bounds(512,4) codegen (60 VGPR, zero spill). 60 <= 64 means HW can
// still co-schedule 8 waves/SIMD -> 4 blocks/CU (32 waves), giving the
// latency-hiding round 6 aimed for without the spills.

namespace {

constexpr int NT = 512;               // 8 waves
constexpr int NP = 16;                // (b,n) pairs per block (same n)
constexpr float INV_STD = 0.9999950000374997f; // 1/sqrt(1+1e-5)

typedef __attribute__((ext_vector_type(8))) short bf16x8;
typedef __attribute__((ext_vector_type(4))) float f32x4;

// d_ws layout (bf16 element offsets). All sections 16B-aligned (off%8==0).
constexpr int OFF_CHEB_A = 0;         // [32co][32k]
constexpr int OFF_CHEB_B = 1024;      // [32co][32k]
constexpr int OFF_A2     = 2048;      // P,Q,R x [64co][96k]
constexpr int OFF_B1     = 20480;     // P,Q,R x [32co][192k]
constexpr int OFF_B2     = 38912;     // P,Q,R x [16co][96k]
constexpr int OFF_S1B    = 43520;     // P,Q,R x [32co][32k] (zero-padded K)
constexpr int OFF_W1     = 46592;     // 113 x [64h][32k]
constexpr int OFF_W2     = 278016;    // 113 x [3o][64k]
// total ws bytes needed: (278016 + 21696) * 2 = 599,424

__device__ __forceinline__ unsigned short f2bf(float f){   // RNE f32->bf16 (prep)
  unsigned int u = __float_as_uint(f);
  u += 0x7fffu + ((u >> 16) & 1u);
  return (unsigned short)(u >> 16);
}
__device__ __forceinline__ unsigned short f2bf_fast(float f){  // native RNE
  return __bfloat16_as_ushort(__float2bfloat16(f));
}
__device__ __forceinline__ f32x4 bcast(float v){ f32x4 r; r[0]=v; r[1]=v; r[2]=v; r[3]=v; return r; }

struct Params {
  const float *x;
  const float *awp,*abp,*awq,*abq,*awr,*abr,*acw,*acb;
  const float *awp2,*abp2,*awq2,*abq2,*awr2,*abr2,*ag,*abeta;
  const float *bwp,*bbp,*bwq,*bbq,*bwr,*bbr,*bcw,*bcb;
  const float *bwp2,*bbp2,*bwq2,*bbq2,*bwr2,*bbr2,*bg,*bbeta;
  const float *w1,*b1,*w2,*b2;
  float *out;
};

// ---------------- prep: one-time weight transpose/convert into ws ----------------
__global__ void stgcn_prep(const Params p, unsigned short* __restrict__ W)
{
  int e = blockIdx.x*256 + threadIdx.x;
  if (e < 2048){                                    // cheb a/b [ci][co] -> [co][ci]
    const float* src = (e < 1024) ? p.acw : p.bcw;
    const int j = e & 1023, co = j >> 5, k = j & 31;
    W[e] = f2bf(src[k*32 + co]);
    return;
  }
  e -= 2048;
  if (e < 18432){                                   // a2: 3 x [64co][96k]
    const int mat = e / 6144, j = e % 6144, co = j / 96, k = j % 96;
    const float* src = mat==0 ? p.awp2 : (mat==1 ? p.awq2 : p.awr2);
    W[OFF_A2 + e] = f2bf(src[k*64 + co]);
    return;
  }
  e -= 18432;
  if (e < 18432){                                   // b1: 3 x [32co][192k]
    const int mat = e / 6144, j = e % 6144, co = j / 192, k = j % 192;
    const float* src = mat==0 ? p.bwp : (mat==1 ? p.bwq : p.bwr);
    W[OFF_B1 + e] = f2bf(src[k*32 + co]);
    return;
  }
  e -= 18432;
  if (e < 4608){                                    // b2: 3 x [16co][96k]
    const int mat = e / 1536, j = e % 1536, co = j / 96, k = j % 96;
    const float* src = mat==0 ? p.bwp2 : (mat==1 ? p.bwq2 : p.bwr2);
    W[OFF_B2 + e] = f2bf(src[k*16 + co]);
    return;
  }
  e -= 4608;
  if (e < 3072){                                    // s1: 3 x [32co][32k], k=tt*8+ci
    const int mat = e / 1024, j = e % 1024, co = j >> 5, k = j & 31;
    const int tt = k >> 3, ci = k & 7;
    const float* src = mat==0 ? p.awp : (mat==1 ? p.awq : p.awr);
    W[OFF_S1B + e] = (ci < 4 && tt < 3) ? f2bf(src[(tt*4+ci)*32 + co])
                                        : (unsigned short)0;
    return;
  }
  e -= 3072;
  if (e < 231424){ W[OFF_W1 + e] = f2bf(p.w1[e]); return; }  // [n][h][f] already B^T
  e -= 231424;
  if (e < 21696){ W[OFF_W2 + e] = f2bf(p.w2[e]); }           // [n][o][k] already B^T
}

// ---------------- generic MFMA stage (j-outer, B preloaded) ----------------
// A row m=(pr,t) in LDS; k-step ks reads 32 contiguous bf16.
// EPI: 0 = relu(acc+bias); 1 = relu(P*sig(Q)+R); 2 = EPI1 then relu(v*bnsc+bnbt).
template<int TOUT, int CIN, int COUT, int NK, int RSTI, int PSTI, int RSTO, int PSTO,
         int KP, int EPI, int MJOBS, int MSTEP>
__device__ __forceinline__ void mfma_stage(const unsigned short* __restrict__ aB,
    const unsigned short* __restrict__ gW, unsigned short* __restrict__ oB,
    const float* __restrict__ gb0, const float* __restrict__ gb1,
    const float* __restrict__ gb2,
    const int Mtile0, const int Ntile, const int lm, const int lk,
    const float bnsc, const float bnbt)
{
  const int col = Ntile*16 + lm;
  bf16x8 wp[NK], wq[NK], wr[NK];
  const unsigned short* wbase = gW + col*KP + lk*8;
  #pragma unroll
  for (int ks = 0; ks < NK; ++ks){
    wp[ks] = *reinterpret_cast<const bf16x8*>(wbase + ks*32);
    if constexpr (EPI >= 1){
      wq[ks] = *reinterpret_cast<const bf16x8*>(wbase +   COUT*KP + ks*32);
      wr[ks] = *reinterpret_cast<const bf16x8*>(wbase + 2*COUT*KP + ks*32);
    }
  }
  const float b0 = gb0[col];
  float b1v = 0.f, b2v = 0.f;
  if constexpr (EPI >= 1){ b1v = gb1[col]; b2v = gb2[col]; }

  #pragma unroll
  for (int j = 0; j < MJOBS; ++j){
    const int Mtile = Mtile0 + j*MSTEP;
    const int m  = Mtile*16 + lm;
    const int pr = m / TOUT;
    const int t  = m - pr*TOUT;
    f32x4 aP = bcast(b0), aQ, aR;
    if constexpr (EPI >= 1){ aQ = bcast(b1v); aR = bcast(b2v); }
    #pragma unroll
    for (int ks = 0; ks < NK; ++ks){
      int elem;
      if constexpr (CIN == 32) elem = pr*PSTI + (t + ks)*RSTI + lk*8;
      else                     elem = pr*PSTI + (t + (ks>>1))*RSTI + (ks&1)*32 + lk*8;
      const bf16x8 a = *reinterpret_cast<const bf16x8*>(aB + elem);
      aP = __builtin_amdgcn_mfma_f32_16x16x32_bf16(a, wp[ks], aP, 0, 0, 0);
      if constexpr (EPI >= 1){
        aQ = __builtin_amdgcn_mfma_f32_16x16x32_bf16(a, wq[ks], aQ, 0, 0, 0);
        aR = __builtin_amdgcn_mfma_f32_16x16x32_bf16(a, wr[ks], aR, 0, 0, 0);
      }
    }
    #pragma unroll
    for (int r = 0; r < 4; ++r){
      const int mo = Mtile*16 + lk*4 + r;
      const int po = mo / TOUT;
      const int to = mo - po*TOUT;
      float v;
      if constexpr (EPI == 0) v = fmaxf(aP[r], 0.f);
      else {
        const float sig = 1.f/(1.f + __expf(-aQ[r]));
        v = fmaxf(fmaf(aP[r], sig, aR[r]), 0.f);
        if constexpr (EPI == 2) v = fmaxf(fmaf(v, bnsc, bnbt), 0.f);
      }
      oB[po*PSTO + to*RSTO + col] = f2bf_fast(v);
    }
  }
}

// ---------------- stage4 (K=192): k-outer, single job/wave, 9 B-frags live ----------------
__device__ __forceinline__ void mfma_stage4(const unsigned short* __restrict__ aB,
    const unsigned short* __restrict__ gW, unsigned short* __restrict__ oB,
    const float* __restrict__ gb0, const float* __restrict__ gb1,
    const float* __restrict__ gb2,
    const int Mtile, const int Ntile, const int lm, const int lk)
{
  const int col = Ntile*16 + lm;
  const unsigned short* wbase = gW + col*192 + lk*8;
  f32x4 aP = bcast(gb0[col]), aQ = bcast(gb1[col]), aR = bcast(gb2[col]);
  const int m  = Mtile*16 + lm;
  const int pr = m >> 2, t = m & 3;
  #pragma unroll
  for (int kb = 0; kb < 2; ++kb){
    bf16x8 wp[3], wq[3], wr[3];
    #pragma unroll
    for (int s = 0; s < 3; ++s){
      const int ks = kb*3 + s;
      wp[s] = *reinterpret_cast<const bf16x8*>(wbase +         ks*32);
      wq[s] = *reinterpret_cast<const bf16x8*>(wbase +  6144 + ks*32); // 32*192
      wr[s] = *reinterpret_cast<const bf16x8*>(wbase + 12288 + ks*32);
    }
    #pragma unroll
    for (int s = 0; s < 3; ++s){
      const int ks = kb*3 + s;
      const int elem = pr*432 + (t + (ks>>1))*72 + (ks&1)*32 + lk*8;
      const bf16x8 a = *reinterpret_cast<const bf16x8*>(aB + elem);
      aP = __builtin_amdgcn_mfma_f32_16x16x32_bf16(a, wp[s], aP, 0,0,0);
      aQ = __builtin_amdgcn_mfma_f32_16x16x32_bf16(a, wq[s], aQ, 0,0,0);
      aR = __builtin_amdgcn_mfma_f32_16x16x32_bf16(a, wr[s], aR, 0,0,0);
    }
  }
  #pragma unroll
  for (int r = 0; r < 4; ++r){
    const int mo = Mtile*16 + lk*4 + r;
    const int po = mo >> 2, to = mo & 3;
    const float sig = 1.f/(1.f + __expf(-aQ[r]));
    const float v = fmaxf(fmaf(aP[r], sig, aR[r]), 0.f);
    oB[po*160 + to*40 + col] = f2bf_fast(v);
  }
}

// ---------------- main fused kernel ----------------
// LDS: sxb 2816B + bufA 13824B + bufB 10240B = 26880B.
// launch_bounds(512,4): VGPR cap 128 -> compiler lands ~60 (round-5 proven),
// 60 <= 64 so HW schedules 8 waves/SIMD -> 4 blocks/CU (wave cap 32).
// Layouts (bf16 elems): sxb [pr*88 + t*8 + ci] (ci<4 real, rest 0, t=10 zero);
// h1/h1c [pr*320 + t*40 + c] (8t,32c); h2 [pr*432 + t*72 + c] (6t,64c);
// h3/h3c [pr*160 + t*40 + c] (4t,32c); h4 [pr*40 + t*16 + c] (flatten order);
// hid [pr*72 + h].
__global__ __launch_bounds__(NT, 4) void stgcn_main(const Params p,
    const unsigned short* __restrict__ W)
{
  __shared__ unsigned short sxb[NP*88];    // 2816 B
  __shared__ unsigned short bufA[6912];    // 13824 B (max: h2 16x432)
  __shared__ unsigned short bufB[5120];    // 10240 B (max: h1c 16x320)

  const int tid = threadIdx.x;
  const int l   = tid & 63;
  const int wid = tid >> 6;     // 0..7
  const int lm  = l & 15;
  const int lk  = l >> 4;
  const int n   = blockIdx.x >> 6;          // b-fastest: 64 consecutive blocks
  const int b0  = (blockIdx.x & 63) * NP;   // share one n (weights L2-hot)

  // x tile: one 8B chunk per (pr, half-slot); even chunks get bf16(x), odd zeros
  for (int i = tid; i < NP*22; i += NT){
    const int pr = i / 22, c = i - pr*22;
    const int t  = c >> 1;
    unsigned short v0=0,v1=0,v2=0,v3=0;
    if (!(c & 1) && t < 10){
      const float4 xf = *reinterpret_cast<const float4*>(
          &p.x[(size_t)(((b0+pr)*10 + t)*113 + n)*4]);
      v0 = f2bf(xf.x); v1 = f2bf(xf.y); v2 = f2bf(xf.z); v3 = f2bf(xf.w);
    }
    ushort4 pk; pk.x=v0; pk.y=v1; pk.z=v2; pk.w=v3;
    *reinterpret_cast<ushort4*>(&sxb[i*4]) = pk;
  }
  __syncthreads();

  // stage1: (10,4)->(8,32) gated conv, K padded 12->32. M=128(8) N=32(2) -> bufA
  mfma_stage<8,32,32,1, 8,88, 40,320, 32, 1, 2,4>(
      sxb, W+OFF_S1B, bufA, p.abp, p.abq, p.abr, wid>>1, wid&1, lm, lk, 0.f, 0.f);
  __syncthreads();

  // cheb1: M=128(8) N=32(2) K=32 -> bufB
  mfma_stage<8,32,32,1, 40,320, 40,320, 32, 0, 2,4>(
      bufA, W+OFF_CHEB_A, bufB, p.acb, p.acb, p.acb, wid>>1, wid&1, lm, lk, 0.f, 0.f);
  __syncthreads();

  // stage3: (8,32)->(6,64) gated + BN(a). M=96(6) N=64(4) K=96 -> bufA
  {
    const float bnsc = INV_STD * p.ag[n], bnbt = p.abeta[n];
    mfma_stage<6,32,64,3, 40,320, 72,432, 96, 2, 3,2>(
        bufB, W+OFF_A2, bufA, p.abp2, p.abq2, p.abr2, wid>>2, wid&3, lm, lk, bnsc, bnbt);
  }
  __syncthreads();

  // stage4: (6,64)->(4,32) gated. M=64(4) N=32(2) K=192 -> bufB
  mfma_stage4(bufA, W+OFF_B1, bufB, p.bbp, p.bbq, p.bbr, wid>>1, wid&1, lm, lk);
  __syncthreads();

  // cheb2: M=64(4) N=32(2) K=32 -> bufA
  mfma_stage<4,32,32,1, 40,160, 40,160, 32, 0, 1,1>(
      bufB, W+OFF_CHEB_B, bufA, p.bcb, p.bcb, p.bcb, wid>>1, wid&1, lm, lk, 0.f, 0.f);
  __syncthreads();

  // stage6: (4,32)->(2,16) gated + BN(b). M=32(2) N=16(1) K=96 -> bufB (h4)
  if (wid < 2){
    const float bnsc = INV_STD * p.bg[n], bnbt = p.bbeta[n];
    mfma_stage<2,32,16,3, 40,160, 16,40, 96, 2, 1,1>(
        bufA, W+OFF_B2, bufB, p.bbp2, p.bbq2, p.bbr2, wid, 0, lm, lk, bnsc, bnbt);
  }
  __syncthreads();

  // mlp1: feat(32) -> hid(64). M=16(1) N=64(4) K=32 -> bufA
  if (wid < 4){
    mfma_stage<1,32,64,1, 16,40, 16,72, 32, 0, 1,1>(
        bufB, W+OFF_W1 + n*2048, bufA, p.b1 + n*64, p.b1, p.b1, 0, wid, lm, lk, 0.f, 0.f);
  }
  __syncthreads();

  // mlp2: hid(64) -> 3. M=16(1), cols 0..2 valid. Store f32 to global.
  if (wid == 0){
    const unsigned short* WM2 = W + OFF_W2 + n*192;
    const float bias = (lm < 3) ? p.b2[n*3 + lm] : 0.f;
    f32x4 acc = bcast(bias);
    #pragma unroll
    for (int ks = 0; ks < 2; ++ks){
      const bf16x8 a = *reinterpret_cast<const bf16x8*>(bufA + lm*72 + ks*32 + lk*8);
      const bf16x8 b = *reinterpret_cast<const bf16x8*>(WM2 + lm*64 + ks*32 + lk*8);
      acc = __builtin_amdgcn_mfma_f32_16x16x32_bf16(a, b, acc, 0, 0, 0);
    }
    if (lm < 3){
      #pragma unroll
      for (int r = 0; r < 4; ++r){
        const int pr = lk*4 + r;
        p.out[(size_t)((b0+pr)*113 + n)*3 + lm] = acc[r];
      }
    }
  }
}

} // namespace

extern "C" void kernel_launch(void* const* d_in, const int* in_sizes, int n_in,
                              void* d_out, int out_size, void* d_ws, size_t ws_size,
                              hipStream_t stream) {
  (void)in_sizes; (void)n_in; (void)ws_size; (void)out_size;
  Params p;
  p.x     = (const float*)d_in[0];
  // d_in[1] = edge_index (unused: ChebConv K=1 keeps only the identity term)
  p.awp   = (const float*)d_in[2];  p.abp   = (const float*)d_in[3];
  p.awq   = (const float*)d_in[4];  p.abq   = (const float*)d_in[5];
  p.awr   = (const float*)d_in[6];  p.abr   = (const float*)d_in[7];
  p.acw   = (const float*)d_in[8];  p.acb   = (const float*)d_in[9];
  p.awp2  = (const float*)d_in[10]; p.abp2  = (const float*)d_in[11];
  p.awq2  = (const float*)d_in[12]; p.abq2  = (const float*)d_in[13];
  p.awr2  = (const float*)d_in[14]; p.abr2  = (const float*)d_in[15];
  p.ag    = (const float*)d_in[16]; p.abeta = (const float*)d_in[17];
  p.bwp   = (const float*)d_in[18]; p.bbp   = (const float*)d_in[19];
  p.bwq   = (const float*)d_in[20]; p.bbq   = (const float*)d_in[21];
  p.bwr   = (const float*)d_in[22]; p.bbr   = (const float*)d_in[23];
  p.bcw   = (const float*)d_in[24]; p.bcb   = (const float*)d_in[25];
  p.bwp2  = (const float*)d_in[26]; p.bbp2  = (const float*)d_in[27];
  p.bwq2  = (const float*)d_in[28]; p.bbq2  = (const float*)d_in[29];
  p.bwr2  = (const float*)d_in[30]; p.bbr2  = (const float*)d_in[31];
  p.bg    = (const float*)d_in[32]; p.bbeta = (const float*)d_in[33];
  p.w1    = (const float*)d_in[34]; p.b1    = (const float*)d_in[35];
  p.w2    = (const float*)d_in[36]; p.b2    = (const float*)d_in[37];
  p.out   = (float*)d_out;

  unsigned short* W = (unsigned short*)d_ws;   // needs 599,424 bytes

  // prep: 299,712 work items
  stgcn_prep<<<1171, 256, 0, stream>>>(p, W);

  const int tiles = 113 * 64;  // 7232 blocks, b fastest within each n
  stgcn_main<<<tiles, NT, 0, stream>>>(p, W);
}

// Round 8
// 145.163 us; speedup vs baseline: 1.7389x; 1.5239x over previous
//
#include <hip/hip_runtime.h>
#include <hip/hip_bf16.h>
#include <math.h>

// STGCN fused, MFMA version, round 8.
// Round 7 post-mortem: NP=16 doubled per-chip fixed cost (frag loads +
// barriers) without raising co-residency -> 221us. Round 5 (NP=32, 145.8us)
// stays the base. Single change here: overlay the x-staging buffer sxb onto
// bufB (sxb dead before cheb1 writes bufB) -> LDS 53,760 -> 48,128 B, which
// crosses the 3-blocks/CU threshold (3x48.1 = 144.4KB <= 160KB). VGPR ~60
// (round-5 proven codegen) <= 85 so 6 waves/SIMD are schedulable -> 24
// waves/CU instead of 16. Everything else byte-identical to round 5.

namespace {

constexpr int NT = 512;               // 8 waves
constexpr int NP = 32;                // (b,n) pairs per block (same n)
constexpr float INV_STD = 0.9999950000374997f; // 1/sqrt(1+1e-5)

typedef __attribute__((ext_vector_type(8))) short bf16x8;
typedef __attribute__((ext_vector_type(4))) float f32x4;

// d_ws layout (bf16 element offsets). All sections 16B-aligned (off%8==0).
constexpr int OFF_CHEB_A = 0;         // [32co][32k]
constexpr int OFF_CHEB_B = 1024;      // [32co][32k]
constexpr int OFF_A2     = 2048;      // P,Q,R x [64co][96k]
constexpr int OFF_B1     = 20480;     // P,Q,R x [32co][192k]
constexpr int OFF_B2     = 38912;     // P,Q,R x [16co][96k]
constexpr int OFF_S1B    = 43520;     // P,Q,R x [32co][32k] (zero-padded K)
constexpr int OFF_W1     = 46592;     // 113 x [64h][32k]
constexpr int OFF_W2     = 278016;    // 113 x [3o][64k]
// total ws bytes needed: (278016 + 21696) * 2 = 599,424

__device__ __forceinline__ unsigned short f2bf(float f){   // RNE f32->bf16 (prep)
  unsigned int u = __float_as_uint(f);
  u += 0x7fffu + ((u >> 16) & 1u);
  return (unsigned short)(u >> 16);
}
__device__ __forceinline__ unsigned short f2bf_fast(float f){  // native RNE
  return __bfloat16_as_ushort(__float2bfloat16(f));
}
__device__ __forceinline__ f32x4 bcast(float v){ f32x4 r; r[0]=v; r[1]=v; r[2]=v; r[3]=v; return r; }

struct Params {
  const float *x;
  const float *awp,*abp,*awq,*abq,*awr,*abr,*acw,*acb;
  const float *awp2,*abp2,*awq2,*abq2,*awr2,*abr2,*ag,*abeta;
  const float *bwp,*bbp,*bwq,*bbq,*bwr,*bbr,*bcw,*bcb;
  const float *bwp2,*bbp2,*bwq2,*bbq2,*bwr2,*bbr2,*bg,*bbeta;
  const float *w1,*b1,*w2,*b2;
  float *out;
};

// ---------------- prep: one-time weight transpose/convert into ws ----------------
__global__ void stgcn_prep(const Params p, unsigned short* __restrict__ W)
{
  int e = blockIdx.x*256 + threadIdx.x;
  if (e < 2048){                                    // cheb a/b [ci][co] -> [co][ci]
    const float* src = (e < 1024) ? p.acw : p.bcw;
    const int j = e & 1023, co = j >> 5, k = j & 31;
    W[e] = f2bf(src[k*32 + co]);
    return;
  }
  e -= 2048;
  if (e < 18432){                                   // a2: 3 x [64co][96k]
    const int mat = e / 6144, j = e % 6144, co = j / 96, k = j % 96;
    const float* src = mat==0 ? p.awp2 : (mat==1 ? p.awq2 : p.awr2);
    W[OFF_A2 + e] = f2bf(src[k*64 + co]);
    return;
  }
  e -= 18432;
  if (e < 18432){                                   // b1: 3 x [32co][192k]
    const int mat = e / 6144, j = e % 6144, co = j / 192, k = j % 192;
    const float* src = mat==0 ? p.bwp : (mat==1 ? p.bwq : p.bwr);
    W[OFF_B1 + e] = f2bf(src[k*32 + co]);
    return;
  }
  e -= 18432;
  if (e < 4608){                                    // b2: 3 x [16co][96k]
    const int mat = e / 1536, j = e % 1536, co = j / 96, k = j % 96;
    const float* src = mat==0 ? p.bwp2 : (mat==1 ? p.bwq2 : p.bwr2);
    W[OFF_B2 + e] = f2bf(src[k*16 + co]);
    return;
  }
  e -= 4608;
  if (e < 3072){                                    // s1: 3 x [32co][32k], k=tt*8+ci
    const int mat = e / 1024, j = e % 1024, co = j >> 5, k = j & 31;
    const int tt = k >> 3, ci = k & 7;
    const float* src = mat==0 ? p.awp : (mat==1 ? p.awq : p.awr);
    W[OFF_S1B + e] = (ci < 4 && tt < 3) ? f2bf(src[(tt*4+ci)*32 + co])
                                        : (unsigned short)0;
    return;
  }
  e -= 3072;
  if (e < 231424){ W[OFF_W1 + e] = f2bf(p.w1[e]); return; }  // [n][h][f] already B^T
  e -= 231424;
  if (e < 21696){ W[OFF_W2 + e] = f2bf(p.w2[e]); }           // [n][o][k] already B^T
}

// ---------------- generic MFMA stage (j-outer, B preloaded) ----------------
// A row m=(pr,t) in LDS; k-step ks reads 32 contiguous bf16.
// EPI: 0 = relu(acc+bias); 1 = relu(P*sig(Q)+R); 2 = EPI1 then relu(v*bnsc+bnbt).
template<int TOUT, int CIN, int COUT, int NK, int RSTI, int PSTI, int RSTO, int PSTO,
         int KP, int EPI, int MJOBS, int MSTEP>
__device__ __forceinline__ void mfma_stage(const unsigned short* __restrict__ aB,
    const unsigned short* __restrict__ gW, unsigned short* __restrict__ oB,
    const float* __restrict__ gb0, const float* __restrict__ gb1,
    const float* __restrict__ gb2,
    const int Mtile0, const int Ntile, const int lm, const int lk,
    const float bnsc, const float bnbt)
{
  const int col = Ntile*16 + lm;
  bf16x8 wp[NK], wq[NK], wr[NK];
  const unsigned short* wbase = gW + col*KP + lk*8;
  #pragma unroll
  for (int ks = 0; ks < NK; ++ks){
    wp[ks] = *reinterpret_cast<const bf16x8*>(wbase + ks*32);
    if constexpr (EPI >= 1){
      wq[ks] = *reinterpret_cast<const bf16x8*>(wbase +   COUT*KP + ks*32);
      wr[ks] = *reinterpret_cast<const bf16x8*>(wbase + 2*COUT*KP + ks*32);
    }
  }
  const float b0 = gb0[col];
  float b1v = 0.f, b2v = 0.f;
  if constexpr (EPI >= 1){ b1v = gb1[col]; b2v = gb2[col]; }

  #pragma unroll
  for (int j = 0; j < MJOBS; ++j){
    const int Mtile = Mtile0 + j*MSTEP;
    const int m  = Mtile*16 + lm;
    const int pr = m / TOUT;
    const int t  = m - pr*TOUT;
    f32x4 aP = bcast(b0), aQ, aR;
    if constexpr (EPI >= 1){ aQ = bcast(b1v); aR = bcast(b2v); }
    #pragma unroll
    for (int ks = 0; ks < NK; ++ks){
      int elem;
      if constexpr (CIN == 32) elem = pr*PSTI + (t + ks)*RSTI + lk*8;
      else                     elem = pr*PSTI + (t + (ks>>1))*RSTI + (ks&1)*32 + lk*8;
      const bf16x8 a = *reinterpret_cast<const bf16x8*>(aB + elem);
      aP = __builtin_amdgcn_mfma_f32_16x16x32_bf16(a, wp[ks], aP, 0, 0, 0);
      if constexpr (EPI >= 1){
        aQ = __builtin_amdgcn_mfma_f32_16x16x32_bf16(a, wq[ks], aQ, 0, 0, 0);
        aR = __builtin_amdgcn_mfma_f32_16x16x32_bf16(a, wr[ks], aR, 0, 0, 0);
      }
    }
    #pragma unroll
    for (int r = 0; r < 4; ++r){
      const int mo = Mtile*16 + lk*4 + r;
      const int po = mo / TOUT;
      const int to = mo - po*TOUT;
      float v;
      if constexpr (EPI == 0) v = fmaxf(aP[r], 0.f);
      else {
        const float sig = 1.f/(1.f + __expf(-aQ[r]));
        v = fmaxf(fmaf(aP[r], sig, aR[r]), 0.f);
        if constexpr (EPI == 2) v = fmaxf(fmaf(v, bnsc, bnbt), 0.f);
      }
      oB[po*PSTO + to*RSTO + col] = f2bf_fast(v);
    }
  }
}

// ---------------- stage4 (K=192): k-outer / j-inner, 9 B-frags live ----------------
__device__ __forceinline__ void mfma_stage4(const unsigned short* __restrict__ aB,
    const unsigned short* __restrict__ gW, unsigned short* __restrict__ oB,
    const float* __restrict__ gb0, const float* __restrict__ gb1,
    const float* __restrict__ gb2,
    const int Mtile0, const int Ntile, const int lm, const int lk)
{
  const int col = Ntile*16 + lm;
  const unsigned short* wbase = gW + col*192 + lk*8;
  f32x4 aP[2], aQ[2], aR[2];
  {
    const float b0 = gb0[col], b1 = gb1[col], b2 = gb2[col];
    #pragma unroll
    for (int j=0;j<2;++j){ aP[j]=bcast(b0); aQ[j]=bcast(b1); aR[j]=bcast(b2); }
  }
  #pragma unroll
  for (int kb = 0; kb < 2; ++kb){
    bf16x8 wp[3], wq[3], wr[3];
    #pragma unroll
    for (int s = 0; s < 3; ++s){
      const int ks = kb*3 + s;
      wp[s] = *reinterpret_cast<const bf16x8*>(wbase +         ks*32);
      wq[s] = *reinterpret_cast<const bf16x8*>(wbase +  6144 + ks*32); // 32*192
      wr[s] = *reinterpret_cast<const bf16x8*>(wbase + 12288 + ks*32);
    }
    #pragma unroll
    for (int j = 0; j < 2; ++j){
      const int Mtile = Mtile0 + j*4;
      const int m  = Mtile*16 + lm;
      const int pr = m >> 2, t = m & 3;
      #pragma unroll
      for (int s = 0; s < 3; ++s){
        const int ks = kb*3 + s;
        const int elem = pr*432 + (t + (ks>>1))*72 + (ks&1)*32 + lk*8;
        const bf16x8 a = *reinterpret_cast<const bf16x8*>(aB + elem);
        aP[j] = __builtin_amdgcn_mfma_f32_16x16x32_bf16(a, wp[s], aP[j], 0,0,0);
        aQ[j] = __builtin_amdgcn_mfma_f32_16x16x32_bf16(a, wq[s], aQ[j], 0,0,0);
        aR[j] = __builtin_amdgcn_mfma_f32_16x16x32_bf16(a, wr[s], aR[j], 0,0,0);
      }
    }
  }
  #pragma unroll
  for (int j = 0; j < 2; ++j){
    const int Mtile = Mtile0 + j*4;
    #pragma unroll
    for (int r = 0; r < 4; ++r){
      const int mo = Mtile*16 + lk*4 + r;
      const int po = mo >> 2, to = mo & 3;
      const float sig = 1.f/(1.f + __expf(-aQ[j][r]));
      const float v = fmaxf(fmaf(aP[j][r], sig, aR[j][r]), 0.f);
      oB[po*160 + to*40 + col] = f2bf_fast(v);
    }
  }
}

// ---------------- main fused kernel ----------------
// LDS: one 48,128 B arena. bufA = smem[0..13823], bufB = smem[13824..24063],
// sxb ALIASES bufB (sxb is consumed by stage1, which completes at the barrier
// before cheb1 first writes bufB). 3 x 48,128 = 144.4KB <= 160KB -> 3 blocks/CU.
// launch_bounds(512,4): round-5 proven ~60 VGPR, no spill; 60 <= 85 so the
// 6 waves/SIMD needed for 3 blocks are schedulable.
// Layouts (bf16 elems): sxb [pr*88 + t*8 + ci] (ci<4 real, rest 0);
// h1/h1c [pr*320 + t*40 + c] (8t,32c); h2 [pr*432 + t*72 + c] (6t,64c);
// h3/h3c [pr*160 + t*40 + c] (4t,32c); h4 [pr*40 + t*16 + c] (flatten order);
// hid [pr*72 + h].
__global__ __launch_bounds__(NT, 4) void stgcn_main(const Params p,
    const unsigned short* __restrict__ W)
{
  __shared__ __align__(16) unsigned short smem[24064];   // 48,128 B
  unsigned short* const bufA = smem;            // 13824 elems (27648 B)
  unsigned short* const bufB = smem + 13824;    // 10240 elems (20480 B)
  unsigned short* const sxb  = bufB;            // 2816 elems, dead before cheb1

  const int tid = threadIdx.x;
  const int l   = tid & 63;
  const int wid = tid >> 6;     // 0..7
  const int lm  = l & 15;
  const int lk  = l >> 4;
  const int n   = blockIdx.x >> 5;          // b-fastest: 32 consecutive blocks
  const int b0  = (blockIdx.x & 31) * NP;   // share one n (weights L2-hot)

  // x tile: one 8B chunk per (pr, half-slot); even chunks get bf16(x), odd zeros
  for (int i = tid; i < NP*22; i += NT){
    const int pr = i / 22, c = i - pr*22;
    const int t  = c >> 1;
    unsigned short v0=0,v1=0,v2=0,v3=0;
    if (!(c & 1) && t < 10){
      const float4 xf = *reinterpret_cast<const float4*>(
          &p.x[(size_t)(((b0+pr)*10 + t)*113 + n)*4]);
      v0 = f2bf(xf.x); v1 = f2bf(xf.y); v2 = f2bf(xf.z); v3 = f2bf(xf.w);
    }
    ushort4 pk; pk.x=v0; pk.y=v1; pk.z=v2; pk.w=v3;
    *reinterpret_cast<ushort4*>(&sxb[i*4]) = pk;
  }
  __syncthreads();

  // stage1: (10,4)->(8,32) gated conv, K padded 12->32. M=256(16) N=32(2) -> bufA
  mfma_stage<8,32,32,1, 8,88, 40,320, 32, 1, 4,4>(
      sxb, W+OFF_S1B, bufA, p.abp, p.abq, p.abr, wid>>1, wid&1, lm, lk, 0.f, 0.f);
  __syncthreads();

  // cheb1: M=256(16) N=32(2) K=32 -> bufB (overwrites sxb region, now dead)
  mfma_stage<8,32,32,1, 40,320, 40,320, 32, 0, 4,4>(
      bufA, W+OFF_CHEB_A, bufB, p.acb, p.acb, p.acb, wid>>1, wid&1, lm, lk, 0.f, 0.f);
  __syncthreads();

  // stage3: (8,32)->(6,64) gated + BN(a). M=192(12) N=64(4) K=96 -> bufA
  {
    const float bnsc = INV_STD * p.ag[n], bnbt = p.abeta[n];
    mfma_stage<6,32,64,3, 40,320, 72,432, 96, 2, 6,2>(
        bufB, W+OFF_A2, bufA, p.abp2, p.abq2, p.abr2, wid>>2, wid&3, lm, lk, bnsc, bnbt);
  }
  __syncthreads();

  // stage4: (6,64)->(4,32) gated. M=128(8) N=32(2) K=192 -> bufB
  mfma_stage4(bufA, W+OFF_B1, bufB, p.bbp, p.bbq, p.bbr, wid>>1, wid&1, lm, lk);
  __syncthreads();

  // cheb2: M=128(8) N=32(2) K=32 -> bufA
  mfma_stage<4,32,32,1, 40,160, 40,160, 32, 0, 2,4>(
      bufB, W+OFF_CHEB_B, bufA, p.bcb, p.bcb, p.bcb, wid>>1, wid&1, lm, lk, 0.f, 0.f);
  __syncthreads();

  // stage6: (4,32)->(2,16) gated + BN(b). M=64(4) N=16(1) K=96 -> bufB (h4)
  if (wid < 4){
    const float bnsc = INV_STD * p.bg[n], bnbt = p.bbeta[n];
    mfma_stage<2,32,16,3, 40,160, 16,40, 96, 2, 1,1>(
        bufA, W+OFF_B2, bufB, p.bbp2, p.bbq2, p.bbr2, wid, 0, lm, lk, bnsc, bnbt);
  }
  __syncthreads();

  // mlp1: feat(32) -> hid(64). M=32(2) N=64(4) K=32 -> bufA
  mfma_stage<1,32,64,1, 16,40, 16,72, 32, 0, 1,1>(
      bufB, W+OFF_W1 + n*2048, bufA, p.b1 + n*64, p.b1, p.b1, wid&1, wid>>1, lm, lk, 0.f, 0.f);
  __syncthreads();

  // mlp2: hid(64) -> 3. M=32(2), cols 0..2 valid (B cols 3..15 read garbage,
  // never written). Store f32 to global.
  if (wid < 2){
    const unsigned short* WM2 = W + OFF_W2 + n*192;
    const int Mtile = wid;
    const float bias = (lm < 3) ? p.b2[n*3 + lm] : 0.f;
    f32x4 acc = bcast(bias);
    #pragma unroll
    for (int ks = 0; ks < 2; ++ks){
      const bf16x8 a = *reinterpret_cast<const bf16x8*>(bufA + (Mtile*16+lm)*72 + ks*32 + lk*8);
      const bf16x8 b = *reinterpret_cast<const bf16x8*>(WM2 + lm*64 + ks*32 + lk*8);
      acc = __builtin_amdgcn_mfma_f32_16x16x32_bf16(a, b, acc, 0, 0, 0);
    }
    if (lm < 3){
      #pragma unroll
      for (int r = 0; r < 4; ++r){
        const int pr = Mtile*16 + lk*4 + r;
        p.out[(size_t)((b0+pr)*113 + n)*3 + lm] = acc[r];
      }
    }
  }
}

} // namespace

extern "C" void kernel_launch(void* const* d_in, const int* in_sizes, int n_in,
                              void* d_out, int out_size, void* d_ws, size_t ws_size,
                              hipStream_t stream) {
  (void)in_sizes; (void)n_in; (void)ws_size; (void)out_size;
  Params p;
  p.x     = (const float*)d_in[0];
  // d_in[1] = edge_index (unused: ChebConv K=1 keeps only the identity term)
  p.awp   = (const float*)d_in[2];  p.abp   = (const float*)d_in[3];
  p.awq   = (const float*)d_in[4];  p.abq   = (const float*)d_in[5];
  p.awr   = (const float*)d_in[6];  p.abr   = (const float*)d_in[7];
  p.acw   = (const float*)d_in[8];  p.acb   = (const float*)d_in[9];
  p.awp2  = (const float*)d_in[10]; p.abp2  = (const float*)d_in[11];
  p.awq2  = (const float*)d_in[12]; p.abq2  = (const float*)d_in[13];
  p.awr2  = (const float*)d_in[14]; p.abr2  = (const float*)d_in[15];
  p.ag    = (const float*)d_in[16]; p.abeta = (const float*)d_in[17];
  p.bwp   = (const float*)d_in[18]; p.bbp   = (const float*)d_in[19];
  p.bwq   = (const float*)d_in[20]; p.bbq   = (const float*)d_in[21];
  p.bwr   = (const float*)d_in[22]; p.bbr   = (const float*)d_in[23];
  p.bcw   = (const float*)d_in[24]; p.bcb   = (const float*)d_in[25];
  p.bwp2  = (const float*)d_in[26]; p.bbp2  = (const float*)d_in[27];
  p.bwq2  = (const float*)d_in[28]; p.bbq2  = (const float*)d_in[29];
  p.bwr2  = (const float*)d_in[30]; p.bbr2  = (const float*)d_in[31];
  p.bg    = (const float*)d_in[32]; p.bbeta = (const float*)d_in[33];
  p.w1    = (const float*)d_in[34]; p.b1    = (const float*)d_in[35];
  p.w2    = (const float*)d_in[36]; p.b2    = (const float*)d_in[37];
  p.out   = (float*)d_out;

  unsigned short* W = (unsigned short*)d_ws;   // needs 599,424 bytes

  // prep: 299,712 work items
  stgcn_prep<<<1171, 256, 0, stream>>>(p, W);

  const int tiles = 113 * 32;  // 3616, b fastest within each n
  stgcn_main<<<tiles, NT, 0, stream>>>(p, W);
}